// Round 12
// baseline (78.071 us; speedup 1.0000x reference)
//
#include <hip/hip_runtime.h>

#define N_NODES   100000
#define N_EDGES   3200000
#define D_FEAT    128

#define N_TIERS   5
#define DSLICE    20000              // 5 x 20000 = 100000; acc = 80 KB f32
#define WINDOW    33344              // bf16 src window = 66688 B; 3 passes
#define N_PASSES  3
#define NCHUNK    160                // 160 x 20000 edges = 3.2M exact
#define EPB       20000              // edges per chunk
#define EPT       20                 // threads 0..999 carry 20 edges each
#define TPB       1024
// grid = 800 = 20 groups x (5 tiers x 8 xcds): tier-siblings share an XCD L2

__device__ __forceinline__ unsigned short f2bf(float f) {
    union { float f; unsigned u; } c; c.f = f;
    unsigned r = c.u + 0x7FFFu + ((c.u >> 16) & 1u);   // round-nearest-even
    return (unsigned short)(r >> 16);
}
__device__ __forceinline__ float bf2f(unsigned short h) {
    union { unsigned u; float f; } c; c.u = ((unsigned)h) << 16; return c.f;
}

// ---------------------------------------------------------------------------
// Kernel 1: per-node feature row-sum -> bf16 table.
// ---------------------------------------------------------------------------
__global__ void __launch_bounds__(256) rowsum_kernel(
    const float* __restrict__ feat,
    unsigned short* __restrict__ rowsum_bf)
{
    const int gid = (int)(blockIdx.x * blockDim.x + threadIdx.x);
    const int row = gid >> 5;
    const int sub = gid & 31;
    if (row >= N_NODES) return;

    const float4 v = reinterpret_cast<const float4*>(
        feat + (size_t)row * D_FEAT)[sub];
    float s = (v.x + v.y) + (v.z + v.w);

    #pragma unroll
    for (int off = 16; off > 0; off >>= 1)
        s += __shfl_xor(s, off, 64);

    if (sub == 0) rowsum_bf[row] = f2bf(s);
}

// ---------------------------------------------------------------------------
// Kernel 2: FUSED LDS-staged-gather + LDS scatter.
// Per block: dst tier accumulator (80 KB f32) + staged src window (65 KB bf16).
// Each thread holds 20 edges in registers across the 3 src passes; gathers
// come from LDS (no L1-miss/MSHR path, no random global loads anywhere).
// XCD-sibling swizzle: the 5 tier-blocks of a chunk land on one XCD.
// ---------------------------------------------------------------------------
__global__ void __launch_bounds__(TPB) scatter_kernel(
    const int* __restrict__ edge_src,
    const int* __restrict__ edge_dst,
    const unsigned short* __restrict__ rowsum_bf,
    unsigned short* __restrict__ copies)
{
    __shared__ __align__(16) float acc[DSLICE];              // 80000 B
    __shared__ __align__(16) unsigned short tbl[WINDOW];     // 66688 B

    const int tid  = (int)threadIdx.x;
    const int bid  = (int)blockIdx.x;
    const int g    = bid / 40;
    const int r    = bid % 40;
    const int tier = r >> 3;                 // 0..4
    const int xcd  = r & 7;
    const int chunk = g * 8 + xcd;           // 0..159
    const int dlo  = tier * DSLICE;

    // zero accumulator (first pass's barrier orders this before any ds_add)
    float4 z; z.x = z.y = z.z = z.w = 0.0f;
    for (int i = tid; i < DSLICE / 4; i += TPB)
        reinterpret_cast<float4*>(acc)[i] = z;

    // ---- load 20 edges into registers (threads 0..999) ----
    const bool va  = (tid < 1000);
    const int base = chunk * EPB + tid * EPT;

    int se[EPT], de[EPT];
    #pragma unroll
    for (int k = 0; k < EPT; ++k) { se[k] = 0; de[k] = 0x7FFFFFFF; }
    if (va) {
        #pragma unroll
        for (int q = 0; q < EPT / 4; ++q) {
            const int4 s4 = *reinterpret_cast<const int4*>(edge_src + base + q * 4);
            const int4 d4 = *reinterpret_cast<const int4*>(edge_dst + base + q * 4);
            se[q*4+0] = s4.x; se[q*4+1] = s4.y; se[q*4+2] = s4.z; se[q*4+3] = s4.w;
            de[q*4+0] = d4.x; de[q*4+1] = d4.y; de[q*4+2] = d4.z; de[q*4+3] = d4.w;
        }
    }

    unsigned short val[EPT];                 // unrolled-only access -> regs
    #pragma unroll
    for (int k = 0; k < EPT; ++k) val[k] = 0;

    // ---- 3 src passes: stage window, gather from LDS ----
    #pragma unroll
    for (int p = 0; p < N_PASSES; ++p) {
        const int slo = p * WINDOW;
        if (p) __syncthreads();              // prior pass's gathers done
        // stage 66688 B = 4168 uint4, coalesced (source is L2/L3-resident)
        for (int i = tid; i < (WINDOW * 2) / 16; i += TPB)
            reinterpret_cast<uint4*>(tbl)[i] =
                reinterpret_cast<const uint4*>(rowsum_bf + slo)[i];
        __syncthreads();

        #pragma unroll
        for (int k = 0; k < EPT; ++k) {
            const unsigned i = (unsigned)(se[k] - slo);
            if (i < (unsigned)WINDOW) val[k] = tbl[i];
        }
    }

    // ---- dst-masked LDS accumulate (once per edge) ----
    #pragma unroll
    for (int k = 0; k < EPT; ++k) {
        const unsigned j = (unsigned)(de[k] - dlo);
        if (j < (unsigned)DSLICE) atomicAdd(&acc[j], bf2f(val[k]));
    }
    __syncthreads();

    // ---- flush accumulator as bf16 partials ----
    unsigned short* __restrict__ dstp =
        copies + ((size_t)tier * NCHUNK + chunk) * DSLICE;
    for (int i = tid; i < DSLICE / 4; i += TPB) {
        const float4 vv = reinterpret_cast<const float4*>(acc)[i];
        ushort4 o;
        o.x = f2bf(vv.x); o.y = f2bf(vv.y); o.z = f2bf(vv.z); o.w = f2bf(vv.w);
        reinterpret_cast<ushort4*>(dstp)[i] = o;
    }
}

// ---------------------------------------------------------------------------
// Kernel 3: reduce the NCHUNK bf16 copies per tier + activations + int cast.
// ---------------------------------------------------------------------------
__global__ void __launch_bounds__(256) reduce_final_kernel(
    const unsigned short* __restrict__ copies,
    int* __restrict__ out)
{
    const int gid = (int)(blockIdx.x * blockDim.x + threadIdx.x);  // ushort4 unit
    if (gid >= N_NODES / 4) return;

    const int tier = gid / (DSLICE / 4);
    const int j4   = gid - tier * (DSLICE / 4);

    float ax = 0.0f, ay = 0.0f, az = 0.0f, aw = 0.0f;
    const ushort4* base = reinterpret_cast<const ushort4*>(copies)
                        + (size_t)tier * NCHUNK * (DSLICE / 4) + j4;
    #pragma unroll 8
    for (int c = 0; c < NCHUNK; ++c) {
        const ushort4 v = base[(size_t)c * (DSLICE / 4)];
        ax += bf2f(v.x); ay += bf2f(v.y); az += bf2f(v.z); aw += bf2f(v.w);
    }

    auto act = [](float x) -> int {
        const float a1 = (x  > 0.0f) ? x  : 0.1f * x;
        const float r2 = 16.0f * a1;
        const float a2 = (r2 > 0.0f) ? r2 : 0.1f * r2;
        return (int)(10.0f * a2);
    };

    int4 o;
    o.x = act(ax); o.y = act(ay); o.z = act(az); o.w = act(aw);
    reinterpret_cast<int4*>(out)[gid] = o;
}

extern "C" void kernel_launch(void* const* d_in, const int* in_sizes, int n_in,
                              void* d_out, int out_size, void* d_ws, size_t ws_size,
                              hipStream_t stream)
{
    const float* feat     = (const float*)d_in[0];
    const int*   edge_src = (const int*)d_in[1];
    const int*   edge_dst = (const int*)d_in[2];
    int*         out      = (int*)d_out;

    char* ws = (char*)d_ws;
    // rowsum_bf: 100000 bf16 used; staging reads up to 3*WINDOW=100032 entries
    // (200064 B) — slack inside the 256 KB pad, never gathered past 99999.
    unsigned short* rowsum_bf = (unsigned short*)(ws);
    unsigned short* copies    = (unsigned short*)(ws + (256 << 10));  // 32 MB

    // Kernel 1: rowsum -> bf16 table
    {
        const int threads = 256;
        const long long total = (long long)N_NODES * 32;
        const int blocks = (int)((total + threads - 1) / threads);
        rowsum_kernel<<<blocks, threads, 0, stream>>>(feat, rowsum_bf);
    }

    // Kernel 2: fused LDS-gather scatter, 800 blocks (perfect XCD swizzle)
    scatter_kernel<<<N_TIERS * NCHUNK, TPB, 0, stream>>>(edge_src, edge_dst,
                                                         rowsum_bf, copies);

    // Kernel 3: reduce + activations + int cast
    {
        const int threads = 256;
        const int blocks = (N_NODES / 4 + threads - 1) / threads;
        reduce_final_kernel<<<blocks, threads, 0, stream>>>(copies, out);
    }
}

// Round 13
// 52.275 us; speedup vs baseline: 1.4935x; 1.4935x over previous
//
#include <hip/hip_runtime.h>

#define N_NODES  100000
#define N_EDGES  3200000
#define D_FEAT   128
#define SLICE    33344         // 3 slices cover 100000; 130.25 KiB LDS
#define SLICE4   (SLICE / 4)
#define N_SLICES 3
#define NCHUNK   80            // edge chunks; grid = 240 = 10 groups of 24
#define EPB      40000         // N_EDGES / NCHUNK; multiple of 8
#define TPB      1024
#define STRIDE   (TPB * 8)     // 8192 edges per iteration per block

__device__ __forceinline__ unsigned short f2bf(float f) {
    union { float f; unsigned u; } c; c.f = f;
    unsigned r = c.u + 0x7FFFu + ((c.u >> 16) & 1u);   // round-nearest-even
    return (unsigned short)(r >> 16);
}
__device__ __forceinline__ float bf2f(unsigned short h) {
    union { unsigned u; float f; } c; c.u = ((unsigned)h) << 16; return c.f;
}

// ---------------------------------------------------------------------------
// Kernel 1: per-node feature row-sum -> bf16 table (halves gather line count:
// 32 entries per 64B line; 200 KB table -> better L1 residency).
// ---------------------------------------------------------------------------
__global__ void __launch_bounds__(256) rowsum_kernel(
    const float* __restrict__ feat,
    unsigned short* __restrict__ rowsum_bf)
{
    const int gid = (int)(blockIdx.x * blockDim.x + threadIdx.x);
    const int row = gid >> 5;
    const int sub = gid & 31;
    if (row >= N_NODES) return;

    const float4 v = reinterpret_cast<const float4*>(
        feat + (size_t)row * D_FEAT)[sub];
    float s = (v.x + v.y) + (v.z + v.w);

    #pragma unroll
    for (int off = 16; off > 0; off >>= 1)
        s += __shfl_xor(s, off, 64);

    if (sub == 0) rowsum_bf[row] = f2bf(s);
}

// ---------------------------------------------------------------------------
// Kernel 2: r6's LDS-privatized scatter, 3-stage pipeline, XCD-sibling
// swizzle — ONLY change vs r6: gathers read the bf16 table (2B loads).
// bid = g*24 + tier*8 + xcd ; slice = tier ; chunk = g*8 + xcd.
// ---------------------------------------------------------------------------
__global__ void __launch_bounds__(TPB) scatter_kernel(
    const int* __restrict__ edge_src,
    const int* __restrict__ edge_dst,
    const unsigned short* __restrict__ rowsum_bf,
    unsigned short* __restrict__ copies)
{
    __shared__ float lds[SLICE];

    const int tid = (int)threadIdx.x;
    const int bid = (int)blockIdx.x;
    const int g   = bid / 24;
    const int r   = bid % 24;
    const int xcd = r & 7;
    const int s   = r >> 3;               // slice (0..2)
    const int b   = g * 8 + xcd;          // chunk (0..79)
    const int lo  = s * SLICE;
    const unsigned len = (unsigned)((N_NODES - lo < SLICE) ? (N_NODES - lo) : SLICE);

    float4 z; z.x = z.y = z.z = z.w = 0.0f;
    for (int i = tid; i < SLICE4; i += TPB)
        reinterpret_cast<float4*>(lds)[i] = z;
    __syncthreads();

    const int begin = b * EPB;
    const int end   = begin + EPB;        // chunks tile N_EDGES exactly

    int eA = begin + tid * 8;             // stage being committed
    int eB = eA + STRIDE;                 // stage being gathered

    int4 dA0, dA1, sA0, sA1, dB0, dB1, sB0, sB1;
    if (eA < end) {
        dA0 = *(const int4*)(edge_dst + eA);     sA0 = *(const int4*)(edge_src + eA);
        dA1 = *(const int4*)(edge_dst + eA + 4); sA1 = *(const int4*)(edge_src + eA + 4);
    }
    if (eB < end) {
        dB0 = *(const int4*)(edge_dst + eB);     sB0 = *(const int4*)(edge_src + eB);
        dB1 = *(const int4*)(edge_dst + eB + 4); sB1 = *(const int4*)(edge_src + eB + 4);
    }

    unsigned jA0, jA1, jA2, jA3, jA4, jA5, jA6, jA7;
    unsigned short wA0, wA1, wA2, wA3, wA4, wA5, wA6, wA7;
    {
        const bool v = (eA < end);
        jA0 = v ? (unsigned)(dA0.x - lo) : 0xFFFFFFFFu;
        jA1 = v ? (unsigned)(dA0.y - lo) : 0xFFFFFFFFu;
        jA2 = v ? (unsigned)(dA0.z - lo) : 0xFFFFFFFFu;
        jA3 = v ? (unsigned)(dA0.w - lo) : 0xFFFFFFFFu;
        jA4 = v ? (unsigned)(dA1.x - lo) : 0xFFFFFFFFu;
        jA5 = v ? (unsigned)(dA1.y - lo) : 0xFFFFFFFFu;
        jA6 = v ? (unsigned)(dA1.z - lo) : 0xFFFFFFFFu;
        jA7 = v ? (unsigned)(dA1.w - lo) : 0xFFFFFFFFu;
        wA0 = (jA0 < len) ? rowsum_bf[sA0.x] : 0;
        wA1 = (jA1 < len) ? rowsum_bf[sA0.y] : 0;
        wA2 = (jA2 < len) ? rowsum_bf[sA0.z] : 0;
        wA3 = (jA3 < len) ? rowsum_bf[sA0.w] : 0;
        wA4 = (jA4 < len) ? rowsum_bf[sA1.x] : 0;
        wA5 = (jA5 < len) ? rowsum_bf[sA1.y] : 0;
        wA6 = (jA6 < len) ? rowsum_bf[sA1.z] : 0;
        wA7 = (jA7 < len) ? rowsum_bf[sA1.w] : 0;
    }

    while (eA < end) {
        // (1) issue idx loads for stage k+2
        const int eC = eB + STRIDE;
        int4 dC0, dC1, sC0, sC1;
        if (eC < end) {
            dC0 = *(const int4*)(edge_dst + eC);     sC0 = *(const int4*)(edge_src + eC);
            dC1 = *(const int4*)(edge_dst + eC + 4); sC1 = *(const int4*)(edge_src + eC + 4);
        }

        // (2) issue gathers for stage k+1 (indices arrived one iter ago)
        const bool v = (eB < end);
        unsigned jB0 = v ? (unsigned)(dB0.x - lo) : 0xFFFFFFFFu;
        unsigned jB1 = v ? (unsigned)(dB0.y - lo) : 0xFFFFFFFFu;
        unsigned jB2 = v ? (unsigned)(dB0.z - lo) : 0xFFFFFFFFu;
        unsigned jB3 = v ? (unsigned)(dB0.w - lo) : 0xFFFFFFFFu;
        unsigned jB4 = v ? (unsigned)(dB1.x - lo) : 0xFFFFFFFFu;
        unsigned jB5 = v ? (unsigned)(dB1.y - lo) : 0xFFFFFFFFu;
        unsigned jB6 = v ? (unsigned)(dB1.z - lo) : 0xFFFFFFFFu;
        unsigned jB7 = v ? (unsigned)(dB1.w - lo) : 0xFFFFFFFFu;
        unsigned short wB0 = (jB0 < len) ? rowsum_bf[sB0.x] : 0;
        unsigned short wB1 = (jB1 < len) ? rowsum_bf[sB0.y] : 0;
        unsigned short wB2 = (jB2 < len) ? rowsum_bf[sB0.z] : 0;
        unsigned short wB3 = (jB3 < len) ? rowsum_bf[sB0.w] : 0;
        unsigned short wB4 = (jB4 < len) ? rowsum_bf[sB1.x] : 0;
        unsigned short wB5 = (jB5 < len) ? rowsum_bf[sB1.y] : 0;
        unsigned short wB6 = (jB6 < len) ? rowsum_bf[sB1.z] : 0;
        unsigned short wB7 = (jB7 < len) ? rowsum_bf[sB1.w] : 0;

        // (3) commit stage k (gathers arrived one iter ago)
        if (jA0 < len) atomicAdd(&lds[jA0], bf2f(wA0));
        if (jA1 < len) atomicAdd(&lds[jA1], bf2f(wA1));
        if (jA2 < len) atomicAdd(&lds[jA2], bf2f(wA2));
        if (jA3 < len) atomicAdd(&lds[jA3], bf2f(wA3));
        if (jA4 < len) atomicAdd(&lds[jA4], bf2f(wA4));
        if (jA5 < len) atomicAdd(&lds[jA5], bf2f(wA5));
        if (jA6 < len) atomicAdd(&lds[jA6], bf2f(wA6));
        if (jA7 < len) atomicAdd(&lds[jA7], bf2f(wA7));

        // rotate stages
        eA = eB; eB = eC;
        dB0 = dC0; dB1 = dC1; sB0 = sC0; sB1 = sC1;
        jA0 = jB0; jA1 = jB1; jA2 = jB2; jA3 = jB3;
        jA4 = jB4; jA5 = jB5; jA6 = jB6; jA7 = jB7;
        wA0 = wB0; wA1 = wB1; wA2 = wB2; wA3 = wB3;
        wA4 = wB4; wA5 = wB5; wA6 = wB6; wA7 = wB7;
    }
    __syncthreads();

    // flush LDS slice as bf16 partials
    unsigned short* __restrict__ dstp = copies + ((size_t)s * NCHUNK + b) * SLICE;
    const int len4 = (int)len >> 2;
    for (int i = tid; i < len4; i += TPB) {
        const float4 vv = reinterpret_cast<const float4*>(lds)[i];
        ushort4 o;
        o.x = f2bf(vv.x); o.y = f2bf(vv.y); o.z = f2bf(vv.z); o.w = f2bf(vv.w);
        reinterpret_cast<ushort4*>(dstp)[i] = o;
    }
}

// ---------------------------------------------------------------------------
// Kernel 3: reduce the NCHUNK bf16 copies per slice + activations + int cast.
// ---------------------------------------------------------------------------
__global__ void __launch_bounds__(256) reduce_final_kernel(
    const unsigned short* __restrict__ copies,
    int* __restrict__ out)
{
    const int i4 = (int)(blockIdx.x * blockDim.x + threadIdx.x);
    if (i4 >= N_NODES / 4) return;

    const int s  = (i4 >= 2 * SLICE4) ? 2 : (i4 >= SLICE4 ? 1 : 0);
    const int j4 = i4 - s * SLICE4;

    float ax = 0.0f, ay = 0.0f, az = 0.0f, aw = 0.0f;
    const ushort4* base = reinterpret_cast<const ushort4*>(copies)
                        + (size_t)s * NCHUNK * SLICE4 + j4;
    #pragma unroll 4
    for (int c = 0; c < NCHUNK; ++c) {
        const ushort4 v = base[(size_t)c * SLICE4];
        ax += bf2f(v.x); ay += bf2f(v.y); az += bf2f(v.z); aw += bf2f(v.w);
    }

    auto act = [](float x) -> int {
        const float a1 = (x  > 0.0f) ? x  : 0.1f * x;
        const float r2 = 16.0f * a1;
        const float a2 = (r2 > 0.0f) ? r2 : 0.1f * r2;
        return (int)(10.0f * a2);
    };

    int4 o;
    o.x = act(ax); o.y = act(ay); o.z = act(az); o.w = act(aw);
    reinterpret_cast<int4*>(out)[i4] = o;
}

extern "C" void kernel_launch(void* const* d_in, const int* in_sizes, int n_in,
                              void* d_out, int out_size, void* d_ws, size_t ws_size,
                              hipStream_t stream)
{
    const float* feat     = (const float*)d_in[0];
    const int*   edge_src = (const int*)d_in[1];
    const int*   edge_dst = (const int*)d_in[2];
    int*         out      = (int*)d_out;

    char* ws = (char*)d_ws;
    unsigned short* rowsum_bf = (unsigned short*)(ws);                // 200 KB (256 KB pad)
    unsigned short* copies    = (unsigned short*)(ws + (256 << 10));  // 16 MB

    // Kernel 1: 32 threads per node -> bf16 rowsum table
    {
        const int threads = 256;
        const long long total = (long long)N_NODES * 32;
        const int blocks = (int)((total + threads - 1) / threads);
        rowsum_kernel<<<blocks, threads, 0, stream>>>(feat, rowsum_bf);
    }

    // Kernel 2: 240 blocks, XCD-sibling swizzled, bf16 gather table
    scatter_kernel<<<N_SLICES * NCHUNK, TPB, 0, stream>>>(edge_src, edge_dst,
                                                          rowsum_bf, copies);

    // Kernel 3: fused reduce + activations + int cast
    {
        const int threads = 256;
        const int blocks = (N_NODES / 4 + threads - 1) / threads;
        reduce_final_kernel<<<blocks, threads, 0, stream>>>(copies, out);
    }
}